// Round 1
// baseline (348.434 us; speedup 1.0000x reference)
//
#include <hip/hip_runtime.h>
#include <cstdint>

#define B_N 16384
#define KN 64
#define DN 256
#define AN 64

// ---------------------------------------------------------------------------
// K0: M = Wq^T @ Wk  (256x256)  and  WgT = transpose(Wgate) (512x256)
// ---------------------------------------------------------------------------
__global__ __launch_bounds__(256) void prep_kernel(const float* __restrict__ Wq,
                                                   const float* __restrict__ Wk,
                                                   const float* __restrict__ Wgate,
                                                   float* __restrict__ M,
                                                   float* __restrict__ WgT) {
    int blk = blockIdx.x;
    int t = threadIdx.x;
    if (blk < DN) {
        // M[i][d] = sum_a Wq[a][i] * Wk[a][d];  i = blk, d = t
        float acc = 0.f;
        #pragma unroll
        for (int a = 0; a < AN; ++a)
            acc += Wq[a * DN + blk] * Wk[a * DN + t];
        M[blk * DN + t] = acc;
    } else {
        int k = blk - DN;                    // 0..511
        WgT[k * DN + t] = Wgate[t * (2 * DN) + k];
    }
}

// ---------------------------------------------------------------------------
// K1: qk[b][d] = sum_i center[b][i] * M[i][d]   ([16384,256] @ [256,256])
// 32 rows/block, 256 threads: thread = (ty 0..7, tx 0..31) -> 4 rows x 8 cols
// ---------------------------------------------------------------------------
__global__ __launch_bounds__(256) void qk_kernel(const float* __restrict__ center,
                                                 const float* __restrict__ M,
                                                 float* __restrict__ qk) {
    __shared__ float xs[32 * DN];            // 32 KB
    int r0 = blockIdx.x * 32;
    int tid = threadIdx.x;

    const float4* src = (const float4*)(center + (size_t)r0 * DN);
    float4* dst = (float4*)xs;
    #pragma unroll
    for (int i = 0; i < 8; ++i)
        dst[tid + 256 * i] = src[tid + 256 * i];
    __syncthreads();

    int ty = tid >> 5, tx = tid & 31;
    float acc[4][8];
    #pragma unroll
    for (int r = 0; r < 4; ++r)
        #pragma unroll
        for (int c = 0; c < 8; ++c) acc[r][c] = 0.f;

    for (int k4 = 0; k4 < DN; k4 += 4) {
        float4 xr[4];
        #pragma unroll
        for (int r = 0; r < 4; ++r)
            xr[r] = *(const float4*)(&xs[(ty * 4 + r) * DN + k4]);
        #pragma unroll
        for (int kk = 0; kk < 4; ++kk) {
            float4 ma = *(const float4*)(&M[(size_t)(k4 + kk) * DN + tx * 8]);
            float4 mb = *(const float4*)(&M[(size_t)(k4 + kk) * DN + tx * 8 + 4]);
            #pragma unroll
            for (int r = 0; r < 4; ++r) {
                float x = (&xr[r].x)[kk];
                acc[r][0] += x * ma.x; acc[r][1] += x * ma.y;
                acc[r][2] += x * ma.z; acc[r][3] += x * ma.w;
                acc[r][4] += x * mb.x; acc[r][5] += x * mb.y;
                acc[r][6] += x * mb.z; acc[r][7] += x * mb.w;
            }
        }
    }
    #pragma unroll
    for (int r = 0; r < 4; ++r) {
        size_t row = (size_t)(r0 + ty * 4 + r);
        float4 o0 = {acc[r][0], acc[r][1], acc[r][2], acc[r][3]};
        float4 o1 = {acc[r][4], acc[r][5], acc[r][6], acc[r][7]};
        *(float4*)(&qk[row * DN + tx * 8]) = o0;
        *(float4*)(&qk[row * DN + tx * 8 + 4]) = o1;
    }
}

// ---------------------------------------------------------------------------
// K2: fused attention. One block per b. neigh[b] (64x256 f32 = 64KB) -> LDS,
// logits -> softmax -> ppi renorm -> context. Single HBM pass over neigh.
// ---------------------------------------------------------------------------
__global__ __launch_bounds__(256) void attn_kernel(const float* __restrict__ neigh,
                                                   const float* __restrict__ ppi,
                                                   const float* __restrict__ qk,
                                                   float* __restrict__ context) {
    __shared__ float sn[KN * DN];            // 64 KB
    __shared__ float sqk[DN];
    __shared__ float slog[KN];
    __shared__ float sattn[KN];

    int b = blockIdx.x;
    int tid = threadIdx.x;

    sqk[tid] = qk[(size_t)b * DN + tid];

    // two-phase reg staging: 16 outstanding dwordx4 loads per thread
    const float4* src = (const float4*)(neigh + (size_t)b * (KN * DN));
    float4* dst = (float4*)sn;
    float4 rr[16];
    #pragma unroll
    for (int i = 0; i < 16; ++i) rr[i] = src[tid + 256 * i];
    #pragma unroll
    for (int i = 0; i < 16; ++i) dst[tid + 256 * i] = rr[i];
    __syncthreads();

    // logits: 64 groups of 4 lanes; group g handles k-row g.
    // d-walk rotated by g so each instr's 64 lanes hit all 32 banks 2x (free).
    int g = tid >> 2, j = tid & 3;
    float acc = 0.f;
    #pragma unroll 16
    for (int m = 0; m < 64; ++m) {
        int s = (m + g) & 63;
        int d = j + 4 * s;
        acc += sn[g * DN + d] * sqk[d];
    }
    acc += __shfl_xor(acc, 1, 64);
    acc += __shfl_xor(acc, 2, 64);
    if (j == 0) slog[g] = acc;
    __syncthreads();

    // softmax + ppi renorm on wave 0 (exact reference semantics)
    if (tid < KN) {
        float l = slog[tid] * 0.125f;        // scale = 64^-0.5
        float mx = l;
        #pragma unroll
        for (int off = 32; off >= 1; off >>= 1)
            mx = fmaxf(mx, __shfl_xor(mx, off, 64));
        float e = expf(l - mx);
        float se = e;
        #pragma unroll
        for (int off = 32; off >= 1; off >>= 1)
            se += __shfl_xor(se, off, 64);
        float p = e / se;                     // softmax
        float t = p * ppi[(size_t)b * KN + tid];
        float st = t;
        #pragma unroll
        for (int off = 32; off >= 1; off >>= 1)
            st += __shfl_xor(st, off, 64);
        sattn[tid] = t / (st + 1e-8f);
    }
    __syncthreads();

    // context[d] = sum_k attn[k] * neigh[k][d]; lanes span d -> conflict-free
    float ctx = 0.f;
    #pragma unroll 16
    for (int k = 0; k < KN; ++k)
        ctx += sattn[k] * sn[k * DN + tid];
    context[(size_t)b * DN + tid] = ctx;
}

// ---------------------------------------------------------------------------
// K3: gate GEMM + blend.  z = [center|context] @ WgT + bgate; out = blend.
// 32 rows/block; thread = (ty,tx) -> 4 rows x 8 cols register tile.
// ---------------------------------------------------------------------------
__global__ __launch_bounds__(256) void gate_kernel(const float* __restrict__ center,
                                                   const float* __restrict__ context,
                                                   const float* __restrict__ WgT,
                                                   const float* __restrict__ bgate,
                                                   float* __restrict__ out) {
    __shared__ float xs[32 * 512];           // 64 KB: per row [center(256)|context(256)]
    int r0 = blockIdx.x * 32;
    int tid = threadIdx.x;

    const float4* c4 = (const float4*)(center + (size_t)r0 * DN);
    const float4* x4 = (const float4*)(context + (size_t)r0 * DN);
    float4* dst = (float4*)xs;
    #pragma unroll
    for (int i = 0; i < 8; ++i) {
        int idx = tid + 256 * i;             // 0..2047
        int r = idx >> 6, c = idx & 63;
        dst[r * 128 + c] = c4[idx];
        dst[r * 128 + 64 + c] = x4[idx];
    }
    __syncthreads();

    int ty = tid >> 5, tx = tid & 31;
    float acc[4][8];
    #pragma unroll
    for (int r = 0; r < 4; ++r)
        #pragma unroll
        for (int c = 0; c < 8; ++c) acc[r][c] = 0.f;

    for (int k4 = 0; k4 < 512; k4 += 4) {
        float4 xr[4];
        #pragma unroll
        for (int r = 0; r < 4; ++r)
            xr[r] = *(const float4*)(&xs[(ty * 4 + r) * 512 + k4]);
        #pragma unroll
        for (int kk = 0; kk < 4; ++kk) {
            float4 wa = *(const float4*)(&WgT[(size_t)(k4 + kk) * DN + tx * 8]);
            float4 wb = *(const float4*)(&WgT[(size_t)(k4 + kk) * DN + tx * 8 + 4]);
            #pragma unroll
            for (int r = 0; r < 4; ++r) {
                float x = (&xr[r].x)[kk];
                acc[r][0] += x * wa.x; acc[r][1] += x * wa.y;
                acc[r][2] += x * wa.z; acc[r][3] += x * wa.w;
                acc[r][4] += x * wb.x; acc[r][5] += x * wb.y;
                acc[r][6] += x * wb.z; acc[r][7] += x * wb.w;
            }
        }
    }

    float4 bg0 = *(const float4*)(&bgate[tx * 8]);
    float4 bg1 = *(const float4*)(&bgate[tx * 8 + 4]);
    #pragma unroll
    for (int r = 0; r < 4; ++r) {
        int rl = ty * 4 + r;
        size_t row = (size_t)(r0 + rl);
        float o[8];
        #pragma unroll
        for (int c = 0; c < 8; ++c) {
            float z = acc[r][c] + ((c < 4) ? (&bg0.x)[c] : (&bg1.x)[c - 4]);
            float gt = 1.0f / (1.0f + expf(-z));
            float cen = xs[rl * 512 + tx * 8 + c];
            float ctx = xs[rl * 512 + 256 + tx * 8 + c];
            o[c] = gt * cen + (1.0f - gt) * ctx;
        }
        float4 o0 = {o[0], o[1], o[2], o[3]};
        float4 o1 = {o[4], o[5], o[6], o[7]};
        *(float4*)(&out[row * DN + tx * 8]) = o0;
        *(float4*)(&out[row * DN + tx * 8 + 4]) = o1;
    }
}

// ---------------------------------------------------------------------------
extern "C" void kernel_launch(void* const* d_in, const int* in_sizes, int n_in,
                              void* d_out, int out_size, void* d_ws, size_t ws_size,
                              hipStream_t stream) {
    const float* center = (const float*)d_in[0];
    const float* neigh  = (const float*)d_in[1];
    const float* ppi    = (const float*)d_in[2];
    const float* Wq     = (const float*)d_in[3];
    const float* Wk     = (const float*)d_in[4];
    const float* Wgate  = (const float*)d_in[5];
    const float* bgate  = (const float*)d_in[6];
    float* out = (float*)d_out;

    char* ws = (char*)d_ws;
    float* M   = (float*)(ws);                                   // 256 KB
    float* WgT = (float*)(ws + 262144);                          // 512 KB
    float* qkb = (float*)(ws + 262144 + 524288);                 // 16 MB
    float* ctx = (float*)(ws + 262144 + 524288 + (size_t)B_N * DN * 4);

    prep_kernel<<<dim3(768), dim3(256), 0, stream>>>(Wq, Wk, Wgate, M, WgT);
    qk_kernel<<<dim3(B_N / 32), dim3(256), 0, stream>>>(center, M, qkb);
    attn_kernel<<<dim3(B_N), dim3(256), 0, stream>>>(neigh, ppi, qkb, ctx);
    gate_kernel<<<dim3(B_N / 32), dim3(256), 0, stream>>>(center, ctx, WgT, bgate, out);
}

// Round 2
// 342.079 us; speedup vs baseline: 1.0186x; 1.0186x over previous
//
#include <hip/hip_runtime.h>
#include <hip/hip_bf16.h>
#include <cstdint>

#define B_N 16384
#define KN 64
#define DN 256
#define AN 64

// pack two f32 -> one u32 of 2x bf16 (RTN); .x lands in low 16 bits
static __device__ inline unsigned int pk2(float a, float b) {
    __hip_bfloat162 h = __float22bfloat162_rn(make_float2(a, b));
    return *reinterpret_cast<unsigned int*>(&h);
}
static __device__ inline float bf_lo(unsigned int v) { return __uint_as_float(v << 16); }
static __device__ inline float bf_hi(unsigned int v) { return __uint_as_float(v & 0xFFFF0000u); }

// ---------------------------------------------------------------------------
// K0: M = Wq^T @ Wk  (256x256)  and  WgT = transpose(Wgate) (512x256)
// ---------------------------------------------------------------------------
__global__ __launch_bounds__(256) void prep_kernel(const float* __restrict__ Wq,
                                                   const float* __restrict__ Wk,
                                                   const float* __restrict__ Wgate,
                                                   float* __restrict__ M,
                                                   float* __restrict__ WgT) {
    int blk = blockIdx.x;
    int t = threadIdx.x;
    if (blk < DN) {
        float acc = 0.f;
        #pragma unroll
        for (int a = 0; a < AN; ++a)
            acc += Wq[a * DN + blk] * Wk[a * DN + t];
        M[blk * DN + t] = acc;
    } else {
        int k = blk - DN;                    // 0..511
        WgT[k * DN + t] = Wgate[t * (2 * DN) + k];
    }
}

// ---------------------------------------------------------------------------
// K1: qk[b][d] = sum_i center[b][i] * M[i][d]   ([16384,256] @ [256,256])
// ---------------------------------------------------------------------------
__global__ __launch_bounds__(256) void qk_kernel(const float* __restrict__ center,
                                                 const float* __restrict__ M,
                                                 float* __restrict__ qk) {
    __shared__ float xs[32 * DN];            // 32 KB
    int r0 = blockIdx.x * 32;
    int tid = threadIdx.x;

    const float4* src = (const float4*)(center + (size_t)r0 * DN);
    float4* dst = (float4*)xs;
    #pragma unroll
    for (int i = 0; i < 8; ++i)
        dst[tid + 256 * i] = src[tid + 256 * i];
    __syncthreads();

    int ty = tid >> 5, tx = tid & 31;
    float acc[4][8];
    #pragma unroll
    for (int r = 0; r < 4; ++r)
        #pragma unroll
        for (int c = 0; c < 8; ++c) acc[r][c] = 0.f;

    for (int k4 = 0; k4 < DN; k4 += 4) {
        float4 xr[4];
        #pragma unroll
        for (int r = 0; r < 4; ++r)
            xr[r] = *(const float4*)(&xs[(ty * 4 + r) * DN + k4]);
        #pragma unroll
        for (int kk = 0; kk < 4; ++kk) {
            float4 ma = *(const float4*)(&M[(size_t)(k4 + kk) * DN + tx * 8]);
            float4 mb = *(const float4*)(&M[(size_t)(k4 + kk) * DN + tx * 8 + 4]);
            #pragma unroll
            for (int r = 0; r < 4; ++r) {
                float x = (&xr[r].x)[kk];
                acc[r][0] += x * ma.x; acc[r][1] += x * ma.y;
                acc[r][2] += x * ma.z; acc[r][3] += x * ma.w;
                acc[r][4] += x * mb.x; acc[r][5] += x * mb.y;
                acc[r][6] += x * mb.z; acc[r][7] += x * mb.w;
            }
        }
    }
    #pragma unroll
    for (int r = 0; r < 4; ++r) {
        size_t row = (size_t)(r0 + ty * 4 + r);
        float4 o0 = {acc[r][0], acc[r][1], acc[r][2], acc[r][3]};
        float4 o1 = {acc[r][4], acc[r][5], acc[r][6], acc[r][7]};
        *(float4*)(&qk[row * DN + tx * 8]) = o0;
        *(float4*)(&qk[row * DN + tx * 8 + 4]) = o1;
    }
}

// ---------------------------------------------------------------------------
// K2: fused attention, bf16 LDS tile (32 KB -> 4 blocks/CU).
// One block per b: stage neigh[b] (64x256) as bf16 pairs, logits -> softmax
// -> ppi renorm -> context. Single HBM pass over neigh.
// ---------------------------------------------------------------------------
__global__ __launch_bounds__(256) void attn_kernel(const float* __restrict__ neigh,
                                                   const float* __restrict__ ppi,
                                                   const float* __restrict__ qk,
                                                   float* __restrict__ context) {
    __shared__ unsigned int sn[KN * (DN / 2)];   // [64][128] bf16-pair words, 32 KB
    __shared__ unsigned int sqk[DN / 2];         // qk as bf16 pairs
    __shared__ float slog[KN];
    __shared__ float sattn[KN];
    __shared__ float scr[DN];                    // context k-half combine

    int b = blockIdx.x;
    int tid = threadIdx.x;

    if (tid < 128) {
        float2 q2 = ((const float2*)(qk + (size_t)b * DN))[tid];
        sqk[tid] = pk2(q2.x, q2.y);
    }

    // reg-staged: issue all 16 loads, then convert+write (T14 split)
    const float4* src = (const float4*)(neigh + (size_t)b * (KN * DN));
    float4 rr[16];
    #pragma unroll
    for (int i = 0; i < 16; ++i) rr[i] = src[tid + 256 * i];
    uint2* dst = (uint2*)sn;
    #pragma unroll
    for (int i = 0; i < 16; ++i)
        dst[tid + 256 * i] = make_uint2(pk2(rr[i].x, rr[i].y), pk2(rr[i].z, rr[i].w));
    __syncthreads();

    // logits: group g (=tid>>2) owns k-row g; 4 lanes j split the 128 pairs.
    // d-walk rotated by g: per-instr banks are 2-way aliased only (free).
    int g = tid >> 2, j = tid & 3;
    float acc = 0.f;
    #pragma unroll
    for (int m = 0; m < 32; ++m) {
        int s = (m + g) & 31;
        int p = j + 4 * s;                   // pair index 0..127
        unsigned int nv = sn[g * 128 + p];
        unsigned int qv = sqk[p];
        acc += bf_lo(nv) * bf_lo(qv) + bf_hi(nv) * bf_hi(qv);
    }
    acc += __shfl_xor(acc, 1, 64);
    acc += __shfl_xor(acc, 2, 64);
    if (j == 0) slog[g] = acc;
    __syncthreads();

    // softmax + ppi renorm on wave 0 (exact reference semantics)
    if (tid < KN) {
        float l = slog[tid] * 0.125f;        // scale = 64^-0.5
        float mx = l;
        #pragma unroll
        for (int off = 32; off >= 1; off >>= 1)
            mx = fmaxf(mx, __shfl_xor(mx, off, 64));
        float e = expf(l - mx);
        float se = e;
        #pragma unroll
        for (int off = 32; off >= 1; off >>= 1)
            se += __shfl_xor(se, off, 64);
        float p = e / se;
        float t = p * ppi[(size_t)b * KN + tid];
        float st = t;
        #pragma unroll
        for (int off = 32; off >= 1; off >>= 1)
            st += __shfl_xor(st, off, 64);
        sattn[tid] = t / (st + 1e-8f);
    }
    __syncthreads();

    // context: thread = (d-pair p, k-half h); 32 pair-reads each, then combine.
    int p = tid & 127, h = tid >> 7;
    float c0 = 0.f, c1 = 0.f;
    #pragma unroll
    for (int kk = 0; kk < 32; ++kk) {
        int k = h * 32 + kk;
        unsigned int nv = sn[k * 128 + p];
        float a = sattn[k];
        c0 += a * bf_lo(nv);
        c1 += a * bf_hi(nv);
    }
    if (h == 1)
        ((float2*)scr)[p] = make_float2(c0, c1);
    __syncthreads();
    if (h == 0) {
        float2 o = ((float2*)scr)[p];
        o.x += c0; o.y += c1;
        ((float2*)(context + (size_t)b * DN))[p] = o;
    }
}

// ---------------------------------------------------------------------------
// K3: gate GEMM + blend.  z = [center|context] @ WgT + bgate; out = blend.
// ---------------------------------------------------------------------------
__global__ __launch_bounds__(256) void gate_kernel(const float* __restrict__ center,
                                                   const float* __restrict__ context,
                                                   const float* __restrict__ WgT,
                                                   const float* __restrict__ bgate,
                                                   float* __restrict__ out) {
    __shared__ float xs[32 * 512];           // 64 KB: per row [center(256)|context(256)]
    int r0 = blockIdx.x * 32;
    int tid = threadIdx.x;

    const float4* c4 = (const float4*)(center + (size_t)r0 * DN);
    const float4* x4 = (const float4*)(context + (size_t)r0 * DN);
    float4* dst = (float4*)xs;
    #pragma unroll
    for (int i = 0; i < 8; ++i) {
        int idx = tid + 256 * i;             // 0..2047
        int r = idx >> 6, c = idx & 63;
        dst[r * 128 + c] = c4[idx];
        dst[r * 128 + 64 + c] = x4[idx];
    }
    __syncthreads();

    int ty = tid >> 5, tx = tid & 31;
    float acc[4][8];
    #pragma unroll
    for (int r = 0; r < 4; ++r)
        #pragma unroll
        for (int c = 0; c < 8; ++c) acc[r][c] = 0.f;

    for (int k4 = 0; k4 < 512; k4 += 4) {
        float4 xr[4];
        #pragma unroll
        for (int r = 0; r < 4; ++r)
            xr[r] = *(const float4*)(&xs[(ty * 4 + r) * 512 + k4]);
        #pragma unroll
        for (int kk = 0; kk < 4; ++kk) {
            float4 wa = *(const float4*)(&WgT[(size_t)(k4 + kk) * DN + tx * 8]);
            float4 wb = *(const float4*)(&WgT[(size_t)(k4 + kk) * DN + tx * 8 + 4]);
            #pragma unroll
            for (int r = 0; r < 4; ++r) {
                float x = (&xr[r].x)[kk];
                acc[r][0] += x * wa.x; acc[r][1] += x * wa.y;
                acc[r][2] += x * wa.z; acc[r][3] += x * wa.w;
                acc[r][4] += x * wb.x; acc[r][5] += x * wb.y;
                acc[r][6] += x * wb.z; acc[r][7] += x * wb.w;
            }
        }
    }

    float4 bg0 = *(const float4*)(&bgate[tx * 8]);
    float4 bg1 = *(const float4*)(&bgate[tx * 8 + 4]);
    #pragma unroll
    for (int r = 0; r < 4; ++r) {
        int rl = ty * 4 + r;
        size_t row = (size_t)(r0 + rl);
        float o[8];
        #pragma unroll
        for (int c = 0; c < 8; ++c) {
            float z = acc[r][c] + ((c < 4) ? (&bg0.x)[c] : (&bg1.x)[c - 4]);
            float gt = 1.0f / (1.0f + expf(-z));
            float cen = xs[rl * 512 + tx * 8 + c];
            float ctx = xs[rl * 512 + 256 + tx * 8 + c];
            o[c] = gt * cen + (1.0f - gt) * ctx;
        }
        float4 o0 = {o[0], o[1], o[2], o[3]};
        float4 o1 = {o[4], o[5], o[6], o[7]};
        *(float4*)(&out[row * DN + tx * 8]) = o0;
        *(float4*)(&out[row * DN + tx * 8 + 4]) = o1;
    }
}

// ---------------------------------------------------------------------------
extern "C" void kernel_launch(void* const* d_in, const int* in_sizes, int n_in,
                              void* d_out, int out_size, void* d_ws, size_t ws_size,
                              hipStream_t stream) {
    const float* center = (const float*)d_in[0];
    const float* neigh  = (const float*)d_in[1];
    const float* ppi    = (const float*)d_in[2];
    const float* Wq     = (const float*)d_in[3];
    const float* Wk     = (const float*)d_in[4];
    const float* Wgate  = (const float*)d_in[5];
    const float* bgate  = (const float*)d_in[6];
    float* out = (float*)d_out;

    char* ws = (char*)d_ws;
    float* M   = (float*)(ws);                                   // 256 KB
    float* WgT = (float*)(ws + 262144);                          // 512 KB
    float* qkb = (float*)(ws + 262144 + 524288);                 // 16 MB
    float* ctx = (float*)(ws + 262144 + 524288 + (size_t)B_N * DN * 4);

    prep_kernel<<<dim3(768), dim3(256), 0, stream>>>(Wq, Wk, Wgate, M, WgT);
    qk_kernel<<<dim3(B_N / 32), dim3(256), 0, stream>>>(center, M, qkb);
    attn_kernel<<<dim3(B_N), dim3(256), 0, stream>>>(neigh, ppi, qkb, ctx);
    gate_kernel<<<dim3(B_N / 32), dim3(256), 0, stream>>>(center, ctx, WgT, bgate, out);
}